// Round 16
// baseline (146.113 us; speedup 1.0000x reference)
//
#include <hip/hip_runtime.h>
#include <hip/hip_bf16.h>
#include <stdint.h>
#include <stddef.h>

typedef __attribute__((ext_vector_type(4))) int int4v;
typedef __attribute__((ext_vector_type(4))) float f32x4;

// global -> LDS direct copy, 16B per lane. LDS dest must be base + lane*16.
__device__ __forceinline__ void gload16(const void* g, void* l) {
    __builtin_amdgcn_global_load_lds(
        (__attribute__((address_space(1))) void*)g,
        (__attribute__((address_space(3))) void*)l,
        16, 0, 0);
}

// ---------------------------------------------------------------------------
__global__ void absmean_partial_k(const float* __restrict__ w,
                                  double* __restrict__ partials) {
    int tid = threadIdx.x;
    size_t base = (size_t)blockIdx.x * 8192 + (size_t)tid * 4;
    float s = 0.f;
#pragma unroll
    for (int i = 0; i < 8; ++i) {
        f32x4 v = *reinterpret_cast<const f32x4*>(w + base + (size_t)i * 1024);
        s += __builtin_fabsf(v.x) + __builtin_fabsf(v.y) +
             __builtin_fabsf(v.z) + __builtin_fabsf(v.w);
    }
    double d = (double)s;
#pragma unroll
    for (int off = 32; off > 0; off >>= 1) d += __shfl_down(d, off, 64);
    __shared__ double red[4];
    int lane = tid & 63, wid = tid >> 6;
    if (lane == 0) red[wid] = d;
    __syncthreads();
    if (tid == 0) partials[blockIdx.x] = red[0] + red[1] + red[2] + red[3];
}

__global__ void absmean_final_k(const double* __restrict__ partials,
                                float* __restrict__ sc, int nparts, int count) {
    int tid = threadIdx.x;
    double d = 0.0;
    for (int i = tid; i < nparts; i += 256) d += partials[i];
#pragma unroll
    for (int off = 32; off > 0; off >>= 1) d += __shfl_down(d, off, 64);
    __shared__ double red[4];
    int lane = tid & 63, wid = tid >> 6;
    if (lane == 0) red[wid] = d;
    __syncthreads();
    if (tid == 0) {
        double total = red[0] + red[1] + red[2] + red[3];
        float scale = (float)(total / (double)count);
        sc[0] = scale;
        sc[1] = scale + 1e-8f;
    }
}

// Quantize w -> ternary int8 {-1,0,1} (EXACT). 16 elems/thread.
__global__ void quantize_w_i8_k(const float* __restrict__ w,
                                char* __restrict__ wq,
                                const float* __restrict__ sc) {
    float speps = sc[1];
    size_t base = ((size_t)blockIdx.x * 256 + threadIdx.x) * 16;
    int p[4] = {0, 0, 0, 0};
#pragma unroll
    for (int i = 0; i < 4; ++i) {
        f32x4 v = *reinterpret_cast<const f32x4*>(w + base + i * 4);
        float e[4] = {v.x, v.y, v.z, v.w};
#pragma unroll
        for (int j = 0; j < 4; ++j) {
            float t = e[j] / speps;
            t = fminf(fmaxf(t, -1.f), 1.f);
            int q = ((int)rintf(t)) & 0xFF;
            p[i] |= q << (j * 8);
        }
    }
    int4v o = {p[0], p[1], p[2], p[3]};
    *reinterpret_cast<int4v*>(wq + base) = o;
}

// Fused per-row x quantization (r15, unchanged): pass 1 rowmax, pass 2
// quantize with the re-read L2-hot. Saves one cold 64MB HBM pass.
__global__ void quantize_x_fused_k(const float* __restrict__ x,
                                   char* __restrict__ xq,
                                   float* __restrict__ maxv, int K) {
    int row = blockIdx.x;
    int tid = threadIdx.x;
    const float* xr = x + (size_t)row * K;
    float m = 0.f;
    for (int base = tid * 4; base < K; base += 1024) {
        f32x4 v = *reinterpret_cast<const f32x4*>(xr + base);
        m = fmaxf(m, fmaxf(fmaxf(__builtin_fabsf(v.x), __builtin_fabsf(v.y)),
                           fmaxf(__builtin_fabsf(v.z), __builtin_fabsf(v.w))));
    }
#pragma unroll
    for (int off = 32; off > 0; off >>= 1) m = fmaxf(m, __shfl_down(m, off, 64));
    __shared__ float red[4];
    int lane = tid & 63, wid = tid >> 6;
    if (lane == 0) red[wid] = m;
    __syncthreads();
    float mv = fmaxf(fmaxf(red[0], red[1]), fmaxf(red[2], red[3]));
    if (tid == 0) maxv[row] = mv;
    float recip = (mv > 0.f) ? (127.f / mv) : 0.f;
    for (int base = tid * 16; base < K; base += 4096) {
        int p[4] = {0, 0, 0, 0};
#pragma unroll
        for (int i = 0; i < 4; ++i) {
            f32x4 v = *reinterpret_cast<const f32x4*>(xr + base + i * 4);
            float e[4] = {v.x, v.y, v.z, v.w};
#pragma unroll
            for (int j = 0; j < 4; ++j) {
                int q = ((int)rintf(e[j] * recip)) & 0xFF;
                p[i] |= q << (j * 8);
            }
        }
        int4v o = {p[0], p[1], p[2], p[3]};
        *reinterpret_cast<int4v*>(xq + (size_t)row * K + base) = o;
    }
}

// ---------------------------------------------------------------------------
// 128x128 8-phase i8 GEMM, 4 waves (256 thr), 64 KiB LDS -> 2 blocks/CU.
// The r12/r14 schedule transfers verbatim (each STG = 2 gloads, identical
// vmcnt ledger: VM4 at p4/p8 forcing 12->8, same prologue/peel). Wave grid
// 2x2, quad = 64x64, per-wave 32x32/quad; acc 64 + operands 48 VGPRs.
// Buffer: A[128 rows][128B] @0 (16KB), B same @16384; BUF1 = +32768.
// 3-bit row-XOR swizzle (row&7 invariant under 16/32/64-row offsets; same
// 0-conflict geometry as r8). mfma_i32_16x16x64_i8, exact i32 accumulate.
#define BUF1 32768

__global__ __launch_bounds__(256, 2) void gemm8_k(
    const char* __restrict__ A,   // [M][K] i8
    const char* __restrict__ B,   // [N][K] i8
    float* __restrict__ C,        // [M][N]
    const float* __restrict__ sc, const float* __restrict__ maxv,
    int M, int N, int K) {
    extern __shared__ char smem[];

    int nwg = gridDim.x, wg = blockIdx.x, swz = wg;
    if ((nwg & 7) == 0) { int cpx = nwg >> 3; swz = (wg & 7) * cpx + (wg >> 3); }
    int nbn = N >> 7;
    int brow = (swz / nbn) << 7, bcol = (swz % nbn) << 7;

    int tid = threadIdx.x, lane = tid & 63, wave = tid >> 6;
    int wm2 = wave >> 1, wn2 = wave & 1;          // 2x2 wave grid in quadrant
    int l15 = lane & 15, l16 = lane >> 4;
    int swl = (l15 & 7) << 4;                     // 3-bit row-XOR swizzle

    // regions per buffer: A = [128 rows][128B] @0, B same @16384.
    // quad qm/qn adds 8192 (64 rows); m2/n2 stride 2048; k-half = ^64.
    int aoffq0 = (wm2 * 32 + l15) * 128 + ((l16 * 16) ^ swl);
    int aoffq1 = aoffq0 + 8192;                   // A-half1 (+64 rows)
    int boffq0 = 16384 + (wn2 * 32 + l15) * 128 + ((l16 * 16) ^ swl);
    int boffq1 = boffq0 + 8192;                   // B-half1

    // staging: dest byte d = tid*16 (linear, 4KB/round); row(d)=tid>>3 in
    // [0,32); source logical = d ^ ((row&7)<<4). Each region half = 64 rows
    // = 2 rounds of 32 rows (2 gload16/thread per STG).
    int sw_t = ((tid >> 3) & 7) << 4;
    int base_e = (tid * 16) ^ sw_t;
    int r0 = base_e >> 7;                         // row 0..31
    int c0 = base_e & 127;                        // i8 col 0..127
    const char* sA = A + (size_t)(brow + r0) * K + c0;
    const char* sB = B + (size_t)(bcol + r0) * K + c0;
    char* dA = smem + tid * 16;
    char* dB = smem + 16384 + tid * 16;

#define STG_A(BUF, H, KT) do { \
    _Pragma("unroll") for (int rnd = 0; rnd < 2; ++rnd) \
        gload16(sA + (size_t)((H) * 64 + rnd * 32) * K + (KT), \
                dA + (BUF) + (H) * 8192 + rnd * 4096); } while (0)
#define STG_B(BUF, H, KT) do { \
    _Pragma("unroll") for (int rnd = 0; rnd < 2; ++rnd) \
        gload16(sB + (size_t)((H) * 64 + rnd * 32) * K + (KT), \
                dB + (BUF) + (H) * 8192 + rnd * 4096); } while (0)

    int4v acc[4][4];   // [qm*2+qn][m2*2+n2], i32x4 accumulators
#pragma unroll
    for (int q = 0; q < 4; ++q)
#pragma unroll
        for (int f = 0; f < 4; ++f) acc[q][f] = (int4v)(0);

    int4v aq[2][2];    // current A-half frags (A0 in p1-p2, A1 in p3-p4)
    int4v bq0[2][2];   // B-half0 frags -- persist p1..p4
    int4v bq1[2][2];   // B-half1 frags -- live p2..p3

#define LDQ_A(BUF, AOFF) do { \
    _Pragma("unroll") for (int m2 = 0; m2 < 2; ++m2) { \
        int _o = (AOFF) + m2 * 2048; \
        aq[m2][0] = *(const int4v*)(smem + (BUF) + _o); \
        aq[m2][1] = *(const int4v*)(smem + (BUF) + (_o ^ 64)); } } while (0)
#define LDQ_B(BUF, BOFF, DST) do { \
    _Pragma("unroll") for (int n2 = 0; n2 < 2; ++n2) { \
        int _o = (BOFF) + n2 * 2048; \
        DST[n2][0] = *(const int4v*)(smem + (BUF) + _o); \
        DST[n2][1] = *(const int4v*)(smem + (BUF) + (_o ^ 64)); } } while (0)
#define MM(Q, BQ) do { \
    __builtin_amdgcn_s_setprio(1); \
    _Pragma("unroll") for (int m2 = 0; m2 < 2; ++m2) \
    _Pragma("unroll") for (int n2 = 0; n2 < 2; ++n2) { \
        acc[Q][m2*2+n2] = __builtin_amdgcn_mfma_i32_16x16x64_i8( \
            aq[m2][0], BQ[n2][0], acc[Q][m2*2+n2], 0, 0, 0); \
        acc[Q][m2*2+n2] = __builtin_amdgcn_mfma_i32_16x16x64_i8( \
            aq[m2][1], BQ[n2][1], acc[Q][m2*2+n2], 0, 0, 0); } \
    __builtin_amdgcn_s_setprio(0); } while (0)
#define BAR __builtin_amdgcn_s_barrier()
#define LGKM asm volatile("s_waitcnt lgkmcnt(0)" ::: "memory")
#define VM4 asm volatile("s_waitcnt vmcnt(4)" ::: "memory")
#define VM0 asm volatile("s_waitcnt vmcnt(0)" ::: "memory")

    // prologue: b0 = slice0 {A0,B0,B1,A1} + b1 = slice1 {A0,B0} (6 STG = 12
    // gloads). VM4 forces all of b0; leaves b1.A0,B0 in flight (invariant).
    STG_A(0, 0, 0); STG_B(0, 0, 0); STG_B(0, 1, 0); STG_A(0, 1, 0);
    STG_A(BUF1, 0, 128); STG_B(BUF1, 0, 128);
    VM4; BAR;

    int nit = K / 256 - 1;  // full iterations; last one peeled
    for (int it = 0; it < nit; ++it) {
        int kb1 = it * 256 + 128;    // slice 2it+1 -> b1 (read p5..p8)
        int kb0 = it * 256 + 256;    // slice 2it+2 -> b0 (read next iter)
        int kb1n = it * 256 + 384;   // slice 2it+3 -> b1 (read next iter)
        // p1: quad(0,0): aq=A0, bq0=B0 | stage b1.B1 (lag 5 -> p6)
        LDQ_A(0, aoffq0); LDQ_B(0, boffq0, bq0);
        STG_B(BUF1, 1, kb1);
        BAR; LGKM; MM(0, bq0); BAR;
        // p2: quad(0,1): bq1=B1 | stage b1.A1 (lag 5 -> p7)
        LDQ_B(0, boffq1, bq1);
        STG_A(BUF1, 1, kb1);
        BAR; LGKM; MM(1, bq1); BAR;
        // p3: quad(1,1): aq=A1 | stage b0'.A0 (lag 6 -> next p1)
        LDQ_A(0, aoffq1);
        STG_A(0, 0, kb0);
        BAR; LGKM; MM(3, bq1); BAR;
        // p4: quad(1,0): pure MFMA | stage b0'.B0 | WAIT: forces all b1
        STG_B(0, 0, kb0);
        BAR; MM(2, bq0); VM4; BAR;   // outstanding: b0'.A0, b0'.B0 only
        // p5: quad(0,0) of b1 | stage b0'.B1
        LDQ_A(BUF1, aoffq0); LDQ_B(BUF1, boffq0, bq0);
        STG_B(0, 1, kb0);
        BAR; LGKM; MM(0, bq0); BAR;
        // p6: quad(0,1) | stage b0'.A1
        LDQ_B(BUF1, boffq1, bq1);
        STG_A(0, 1, kb0);
        BAR; LGKM; MM(1, bq1); BAR;
        // p7: quad(1,1) | stage b1'.A0
        LDQ_A(BUF1, aoffq1);
        STG_A(BUF1, 0, kb1n);
        BAR; LGKM; MM(3, bq1); BAR;
        // p8: quad(1,0): pure MFMA | stage b1'.B0 | WAIT: forces all b0'
        STG_B(BUF1, 0, kb1n);
        BAR; MM(2, bq0); VM4; BAR;   // outstanding: b1'.A0, b1'.B0 only
    }
    // peeled last iteration (slices 2*nit, 2*nit+1): stage only b1.B1/A1
    {
        int kb1 = nit * 256 + 128;
        LDQ_A(0, aoffq0); LDQ_B(0, boffq0, bq0);
        STG_B(BUF1, 1, kb1);
        BAR; LGKM; MM(0, bq0); BAR;
        LDQ_B(0, boffq1, bq1);
        STG_A(BUF1, 1, kb1);
        BAR; LGKM; MM(1, bq1); BAR;
        LDQ_A(0, aoffq1);
        BAR; LGKM; MM(3, bq1); BAR;
        BAR; MM(2, bq0); VM0; BAR;   // drain: all of b1 landed
        LDQ_A(BUF1, aoffq0); LDQ_B(BUF1, boffq0, bq0);
        BAR; LGKM; MM(0, bq0); BAR;
        LDQ_B(BUF1, boffq1, bq1);
        BAR; LGKM; MM(1, bq1); BAR;
        LDQ_A(BUF1, aoffq1);
        BAR; LGKM; MM(3, bq1); BAR;
        BAR; MM(2, bq0);
    }

    // epilogue: C = acc_i32 * (maxv[row] * s / 127)
    float s127 = sc[0] * (1.0f / 127.0f);
#pragma unroll
    for (int qm = 0; qm < 2; ++qm)
#pragma unroll
        for (int m2 = 0; m2 < 2; ++m2)
#pragma unroll
            for (int r = 0; r < 4; ++r) {
                int grow = brow + qm * 64 + wm2 * 32 + m2 * 16 + l16 * 4 + r;
                float rs = maxv[grow] * s127;
#pragma unroll
                for (int qn = 0; qn < 2; ++qn)
#pragma unroll
                    for (int n2 = 0; n2 < 2; ++n2) {
                        int gcol = bcol + qn * 64 + wn2 * 32 + n2 * 16 + l15;
                        C[(size_t)grow * N + gcol] =
                            (float)acc[qm * 2 + qn][m2 * 2 + n2][r] * rs;
                    }
            }
}

// ---------------------------------------------------------------------------
// Fallback: fused f32 tile GEMM with on-the-fly quantization (tiny-ws path).
__global__ void gemm_fallback_k(const float* __restrict__ X,
                                const float* __restrict__ W,
                                float* __restrict__ C,
                                const float* __restrict__ sc,
                                int M, int N, int K) {
    __shared__ float Xs[32][33];
    __shared__ float Ws[32][33];
    float speps = sc[1];
    int nbn = N / 32;
    int brow = (blockIdx.x / nbn) * 32;
    int bcol = (blockIdx.x % nbn) * 32;
    int tx = threadIdx.x & 31;
    int ty4 = threadIdx.x >> 5;
    float acc[4] = {0.f, 0.f, 0.f, 0.f};
    for (int kt = 0; kt < K; kt += 32) {
#pragma unroll
        for (int i = 0; i < 4; ++i) {
            int idx = threadIdx.x + i * 256;
            int r = idx >> 5, c = idx & 31;
            Xs[r][c] = X[(size_t)(brow + r) * K + kt + c];
            float wv = W[(size_t)(bcol + r) * K + kt + c];
            float t = wv / speps;
            t = fminf(fmaxf(t, -1.f), 1.f);
            Ws[r][c] = rintf(t);
        }
        __syncthreads();
#pragma unroll
        for (int kk = 0; kk < 32; ++kk) {
            float wv = Ws[tx][kk];
#pragma unroll
            for (int i = 0; i < 4; ++i) acc[i] += Xs[ty4 * 4 + i][kk] * wv;
        }
        __syncthreads();
    }
    float scale = sc[0];
#pragma unroll
    for (int i = 0; i < 4; ++i)
        C[(size_t)(brow + ty4 * 4 + i) * N + (bcol + tx)] = acc[i] * scale;
}

// ---------------------------------------------------------------------------
extern "C" void kernel_launch(void* const* d_in, const int* in_sizes, int n_in,
                              void* d_out, int out_size, void* d_ws,
                              size_t ws_size, hipStream_t stream) {
    const float* x = (const float*)d_in[0];   // [B,S,K] f32
    const float* w = (const float*)d_in[1];   // [N,K]   f32
    float* out = (float*)d_out;               // [B,S,N] f32

    const int K = 4096;
    const int N = 4096;
    int xn = in_sizes[0];                     // M*K
    int wn = in_sizes[1];                     // N*K
    int M = xn / K;

    const int NPART = 2048;
    size_t off_sc = (size_t)NPART * 8;        // 16384
    size_t off_mx = off_sc + 64;              // maxv: M floats
    size_t off_xq = off_mx + (size_t)M * 4;
    off_xq = (off_xq + 63) & ~(size_t)63;
    size_t need = off_xq + (size_t)xn + (size_t)wn;  // i8 buffers

    bool shape_ok = (M % 128 == 0) && (N % 128 == 0) && (K % 256 == 0) &&
                    (K >= 512);

    if (ws_size >= need && shape_ok) {
        double* partials = (double*)d_ws;
        float* sc = (float*)((char*)d_ws + off_sc);
        float* maxv = (float*)((char*)d_ws + off_mx);
        char* xq = (char*)d_ws + off_xq;
        char* wq = xq + xn;

        absmean_partial_k<<<NPART, 256, 0, stream>>>(w, partials);
        absmean_final_k<<<1, 256, 0, stream>>>(partials, sc, NPART, wn);
        quantize_w_i8_k<<<wn / 4096, 256, 0, stream>>>(w, wq, sc);
        quantize_x_fused_k<<<M, 256, 0, stream>>>(x, xq, maxv, K);

        hipFuncSetAttribute(reinterpret_cast<const void*>(gemm8_k),
                            hipFuncAttributeMaxDynamicSharedMemorySize, 65536);
        dim3 grid((M / 128) * (N / 128));
        gemm8_k<<<grid, 256, 65536, stream>>>(xq, wq, out, sc, maxv, M, N, K);
    } else {
        double* partials = (double*)d_out;
        float* sc = (float*)d_ws;
        absmean_partial_k<<<NPART, 256, 0, stream>>>(w, partials);
        absmean_final_k<<<1, 256, 0, stream>>>(partials, sc, NPART, wn);
        dim3 grid((M / 32) * (N / 32));
        gemm_fallback_k<<<grid, 256, 0, stream>>>(x, w, out, sc, M, N, K);
    }
}

// Round 17
// 113.755 us; speedup vs baseline: 1.2845x; 1.2845x over previous
//
#include <hip/hip_runtime.h>
#include <hip/hip_bf16.h>
#include <stdint.h>
#include <stddef.h>

typedef __attribute__((ext_vector_type(4))) int int4v;
typedef __attribute__((ext_vector_type(4))) float f32x4;

// global -> LDS direct copy, 16B per lane. LDS dest must be base + lane*16.
__device__ __forceinline__ void gload16(const void* g, void* l) {
    __builtin_amdgcn_global_load_lds(
        (__attribute__((address_space(1))) void*)g,
        (__attribute__((address_space(3))) void*)l,
        16, 0, 0);
}

// ---------------------------------------------------------------------------
__global__ void absmean_partial_k(const float* __restrict__ w,
                                  double* __restrict__ partials) {
    int tid = threadIdx.x;
    size_t base = (size_t)blockIdx.x * 8192 + (size_t)tid * 4;
    float s = 0.f;
#pragma unroll
    for (int i = 0; i < 8; ++i) {
        f32x4 v = *reinterpret_cast<const f32x4*>(w + base + (size_t)i * 1024);
        s += __builtin_fabsf(v.x) + __builtin_fabsf(v.y) +
             __builtin_fabsf(v.z) + __builtin_fabsf(v.w);
    }
    double d = (double)s;
#pragma unroll
    for (int off = 32; off > 0; off >>= 1) d += __shfl_down(d, off, 64);
    __shared__ double red[4];
    int lane = tid & 63, wid = tid >> 6;
    if (lane == 0) red[wid] = d;
    __syncthreads();
    if (tid == 0) partials[blockIdx.x] = red[0] + red[1] + red[2] + red[3];
}

__global__ void absmean_final_k(const double* __restrict__ partials,
                                float* __restrict__ sc, int nparts, int count) {
    int tid = threadIdx.x;
    double d = 0.0;
    for (int i = tid; i < nparts; i += 256) d += partials[i];
#pragma unroll
    for (int off = 32; off > 0; off >>= 1) d += __shfl_down(d, off, 64);
    __shared__ double red[4];
    int lane = tid & 63, wid = tid >> 6;
    if (lane == 0) red[wid] = d;
    __syncthreads();
    if (tid == 0) {
        double total = red[0] + red[1] + red[2] + red[3];
        float scale = (float)(total / (double)count);
        sc[0] = scale;
        sc[1] = scale + 1e-8f;
    }
}

// Quantize w -> ternary int8 {-1,0,1} (EXACT). 16 elems/thread.
__global__ void quantize_w_i8_k(const float* __restrict__ w,
                                char* __restrict__ wq,
                                const float* __restrict__ sc) {
    float speps = sc[1];
    size_t base = ((size_t)blockIdx.x * 256 + threadIdx.x) * 16;
    int p[4] = {0, 0, 0, 0};
#pragma unroll
    for (int i = 0; i < 4; ++i) {
        f32x4 v = *reinterpret_cast<const f32x4*>(w + base + i * 4);
        float e[4] = {v.x, v.y, v.z, v.w};
#pragma unroll
        for (int j = 0; j < 4; ++j) {
            float t = e[j] / speps;
            t = fminf(fmaxf(t, -1.f), 1.f);
            int q = ((int)rintf(t)) & 0xFF;
            p[i] |= q << (j * 8);
        }
    }
    int4v o = {p[0], p[1], p[2], p[3]};
    *reinterpret_cast<int4v*>(wq + base) = o;
}

// Fused per-row x quantization (r15, unchanged): pass 1 rowmax, pass 2
// quantize with the re-read L2-hot. Saves one cold 64MB HBM pass.
__global__ void quantize_x_fused_k(const float* __restrict__ x,
                                   char* __restrict__ xq,
                                   float* __restrict__ maxv, int K) {
    int row = blockIdx.x;
    int tid = threadIdx.x;
    const float* xr = x + (size_t)row * K;
    float m = 0.f;
    for (int base = tid * 4; base < K; base += 1024) {
        f32x4 v = *reinterpret_cast<const f32x4*>(xr + base);
        m = fmaxf(m, fmaxf(fmaxf(__builtin_fabsf(v.x), __builtin_fabsf(v.y)),
                           fmaxf(__builtin_fabsf(v.z), __builtin_fabsf(v.w))));
    }
#pragma unroll
    for (int off = 32; off > 0; off >>= 1) m = fmaxf(m, __shfl_down(m, off, 64));
    __shared__ float red[4];
    int lane = tid & 63, wid = tid >> 6;
    if (lane == 0) red[wid] = m;
    __syncthreads();
    float mv = fmaxf(fmaxf(red[0], red[1]), fmaxf(red[2], red[3]));
    if (tid == 0) maxv[row] = mv;
    float recip = (mv > 0.f) ? (127.f / mv) : 0.f;
    for (int base = tid * 16; base < K; base += 4096) {
        int p[4] = {0, 0, 0, 0};
#pragma unroll
        for (int i = 0; i < 4; ++i) {
            f32x4 v = *reinterpret_cast<const f32x4*>(xr + base + i * 4);
            float e[4] = {v.x, v.y, v.z, v.w};
#pragma unroll
            for (int j = 0; j < 4; ++j) {
                int q = ((int)rintf(e[j] * recip)) & 0xFF;
                p[i] |= q << (j * 8);
            }
        }
        int4v o = {p[0], p[1], p[2], p[3]};
        *reinterpret_cast<int4v*>(xq + (size_t)row * K + base) = o;
    }
}

// ---------------------------------------------------------------------------
// 256x256 8-phase i8 GEMM (r15 revert), ONE change: the explicit
// lgkmcnt(0) drains before each MFMA cluster are REMOVED. hipcc inserts
// its own minimal counted lgkmcnt waits before each ds_read-dependent MFMA
// (m97 asm evidence); the explicit full drain was a redundant stall stacked
// on top. Correctness: every ds_read is consumed by an MFMA within the same
// phase, so compiler waits retire all reads before the phase-closing
// barrier -- the cross-wave W-A-R guard vs next-phase gload_lds writes is
// preserved. vmcnt ledger/barriers/staging/swizzle byte-identical to r15.
#define BUF1 65536

__global__ __launch_bounds__(512, 2) void gemm8_k(
    const char* __restrict__ A,   // [M][K] i8
    const char* __restrict__ B,   // [N][K] i8
    float* __restrict__ C,        // [M][N]
    const float* __restrict__ sc, const float* __restrict__ maxv,
    int M, int N, int K) {
    extern __shared__ char smem[];

    int nwg = gridDim.x, wg = blockIdx.x, swz = wg;
    if ((nwg & 7) == 0) { int cpx = nwg >> 3; swz = (wg & 7) * cpx + (wg >> 3); }
    int nbn = N >> 8;
    int brow = (swz / nbn) << 8, bcol = (swz % nbn) << 8;

    int tid = threadIdx.x, lane = tid & 63, wave = tid >> 6;
    int wm2 = wave >> 2, wn4 = wave & 3;          // 2x4 wave grid in quadrant
    int l15 = lane & 15, l16 = lane >> 4;
    int swl = (l15 & 7) << 4;                     // 3-bit row-XOR swizzle

    // regions per buffer: A = [256 rows][128B] @0, B same @32768.
    int aoffq0 = (wm2 * 64 + l15) * 128 + ((l16 * 16) ^ swl);
    int aoffq1 = aoffq0 + 16384;                  // A-half1 (+128 rows)
    int boffq0 = 32768 + (wn4 * 32 + l15) * 128 + ((l16 * 16) ^ swl);
    int boffq1 = boffq0 + 16384;                  // B-half1

    // staging: dest byte d = tid*16 (linear); source logical = d ^ ((row&7)<<4)
    int sw_t = ((tid >> 3) & 7) << 4;
    int base_e = (tid * 16) ^ sw_t;
    int r0 = base_e >> 7;                         // row 0..63
    int c0 = base_e & 127;                        // i8 col 0..127
    const char* sA = A + (size_t)(brow + r0) * K + c0;
    const char* sB = B + (size_t)(bcol + r0) * K + c0;
    size_t r64 = (size_t)64 * K, r128 = (size_t)128 * K;
    char* dA = smem + tid * 16;
    char* dB = smem + 32768 + tid * 16;

#define STG_A(BUF, H, KT) do { \
    const char* _s = sA + (size_t)(H) * r128 + (KT); \
    char* _d = dA + (BUF) + (H) * 16384; \
    gload16(_s, _d); gload16(_s + r64, _d + 8192); } while (0)
#define STG_B(BUF, H, KT) do { \
    const char* _s = sB + (size_t)(H) * r128 + (KT); \
    char* _d = dB + (BUF) + (H) * 16384; \
    gload16(_s, _d); gload16(_s + r64, _d + 8192); } while (0)

    int4v acc[4][8];   // [qm*2+qn][m2*2+n2], i32x4 accumulators
#pragma unroll
    for (int q = 0; q < 4; ++q)
#pragma unroll
        for (int f = 0; f < 8; ++f) acc[q][f] = (int4v)(0);

    int4v aq[4][2];    // current A-half frags (A0 in p1-p2, A1 in p3-p4)
    int4v bq0[2][2];   // B-half0 frags -- persist p1..p4
    int4v bq1[2][2];   // B-half1 frags -- live p2..p3

#define LDQ_A(BUF, AOFF) do { \
    _Pragma("unroll") for (int m2 = 0; m2 < 4; ++m2) { \
        int _o = (AOFF) + m2 * 2048; \
        aq[m2][0] = *(const int4v*)(smem + (BUF) + _o); \
        aq[m2][1] = *(const int4v*)(smem + (BUF) + (_o ^ 64)); } } while (0)
#define LDQ_B(BUF, BOFF, DST) do { \
    _Pragma("unroll") for (int n2 = 0; n2 < 2; ++n2) { \
        int _o = (BOFF) + n2 * 2048; \
        DST[n2][0] = *(const int4v*)(smem + (BUF) + _o); \
        DST[n2][1] = *(const int4v*)(smem + (BUF) + (_o ^ 64)); } } while (0)
#define MM(Q, BQ) do { \
    __builtin_amdgcn_s_setprio(1); \
    _Pragma("unroll") for (int m2 = 0; m2 < 4; ++m2) \
    _Pragma("unroll") for (int n2 = 0; n2 < 2; ++n2) { \
        acc[Q][m2*2+n2] = __builtin_amdgcn_mfma_i32_16x16x64_i8( \
            aq[m2][0], BQ[n2][0], acc[Q][m2*2+n2], 0, 0, 0); \
        acc[Q][m2*2+n2] = __builtin_amdgcn_mfma_i32_16x16x64_i8( \
            aq[m2][1], BQ[n2][1], acc[Q][m2*2+n2], 0, 0, 0); } \
    __builtin_amdgcn_s_setprio(0); } while (0)
#define BAR __builtin_amdgcn_s_barrier()
#define VM4 asm volatile("s_waitcnt vmcnt(4)" ::: "memory")
#define VM0 asm volatile("s_waitcnt vmcnt(0)" ::: "memory")

    // prologue: b0 = slice0 {A0,B0,B1,A1} + b1 = slice1 {A0,B0} (6 STG).
    // VM4 forces all of b0; leaves b1.A0,B0 in flight (p1-entry invariant).
    STG_A(0, 0, 0); STG_B(0, 0, 0); STG_B(0, 1, 0); STG_A(0, 1, 0);
    STG_A(BUF1, 0, 128); STG_B(BUF1, 0, 128);
    VM4; BAR;

    int nit = K / 256 - 1;  // full iterations; last one peeled
    for (int it = 0; it < nit; ++it) {
        int kb1 = it * 256 + 128;    // slice 2it+1 -> b1 (read p5..p8)
        int kb0 = it * 256 + 256;    // slice 2it+2 -> b0 (read next iter)
        int kb1n = it * 256 + 384;   // slice 2it+3 -> b1 (read next iter)
        // p1: quad(0,0): aq=A0, bq0=B0 | stage b1.B1 (lag 5 -> p6)
        LDQ_A(0, aoffq0); LDQ_B(0, boffq0, bq0);
        STG_B(BUF1, 1, kb1);
        BAR; MM(0, bq0); BAR;
        // p2: quad(0,1): bq1=B1 | stage b1.A1 (lag 5 -> p7)
        LDQ_B(0, boffq1, bq1);
        STG_A(BUF1, 1, kb1);
        BAR; MM(1, bq1); BAR;
        // p3: quad(1,1): aq=A1 | stage b0'.A0 (lag 6 -> next p1)
        LDQ_A(0, aoffq1);
        STG_A(0, 0, kb0);
        BAR; MM(3, bq1); BAR;
        // p4: quad(1,0): pure MFMA | stage b0'.B0 | WAIT: forces all b1
        STG_B(0, 0, kb0);
        BAR; MM(2, bq0); VM4; BAR;   // outstanding: b0'.A0, b0'.B0 only
        // p5: quad(0,0) of b1 | stage b0'.B1
        LDQ_A(BUF1, aoffq0); LDQ_B(BUF1, boffq0, bq0);
        STG_B(0, 1, kb0);
        BAR; MM(0, bq0); BAR;
        // p6: quad(0,1) | stage b0'.A1
        LDQ_B(BUF1, boffq1, bq1);
        STG_A(0, 1, kb0);
        BAR; MM(1, bq1); BAR;
        // p7: quad(1,1) | stage b1'.A0
        LDQ_A(BUF1, aoffq1);
        STG_A(BUF1, 0, kb1n);
        BAR; MM(3, bq1); BAR;
        // p8: quad(1,0): pure MFMA | stage b1'.B0 | WAIT: forces all b0'
        STG_B(BUF1, 0, kb1n);
        BAR; MM(2, bq0); VM4; BAR;   // outstanding: b1'.A0, b1'.B0 only
    }
    // peeled last iteration (slices 2*nit, 2*nit+1): stage only b1.B1/A1
    {
        int kb1 = nit * 256 + 128;
        LDQ_A(0, aoffq0); LDQ_B(0, boffq0, bq0);
        STG_B(BUF1, 1, kb1);
        BAR; MM(0, bq0); BAR;
        LDQ_B(0, boffq1, bq1);
        STG_A(BUF1, 1, kb1);
        BAR; MM(1, bq1); BAR;
        LDQ_A(0, aoffq1);
        BAR; MM(3, bq1); BAR;
        BAR; MM(2, bq0); VM0; BAR;   // drain: all of b1 landed
        LDQ_A(BUF1, aoffq0); LDQ_B(BUF1, boffq0, bq0);
        BAR; MM(0, bq0); BAR;
        LDQ_B(BUF1, boffq1, bq1);
        BAR; MM(1, bq1); BAR;
        LDQ_A(BUF1, aoffq1);
        BAR; MM(3, bq1); BAR;
        BAR; MM(2, bq0);
    }

    // epilogue: C = acc_i32 * (maxv[row] * s / 127)
    float s127 = sc[0] * (1.0f / 127.0f);
#pragma unroll
    for (int qm = 0; qm < 2; ++qm)
#pragma unroll
        for (int m2 = 0; m2 < 4; ++m2)
#pragma unroll
            for (int r = 0; r < 4; ++r) {
                int grow = brow + qm * 128 + wm2 * 64 + m2 * 16 + l16 * 4 + r;
                float rs = maxv[grow] * s127;
#pragma unroll
                for (int qn = 0; qn < 2; ++qn)
#pragma unroll
                    for (int n2 = 0; n2 < 2; ++n2) {
                        int gcol = bcol + qn * 128 + wn4 * 32 + n2 * 16 + l15;
                        C[(size_t)grow * N + gcol] =
                            (float)acc[qm * 2 + qn][m2 * 2 + n2][r] * rs;
                    }
            }
}

// ---------------------------------------------------------------------------
// Fallback: fused f32 tile GEMM with on-the-fly quantization (tiny-ws path).
__global__ void gemm_fallback_k(const float* __restrict__ X,
                                const float* __restrict__ W,
                                float* __restrict__ C,
                                const float* __restrict__ sc,
                                int M, int N, int K) {
    __shared__ float Xs[32][33];
    __shared__ float Ws[32][33];
    float speps = sc[1];
    int nbn = N / 32;
    int brow = (blockIdx.x / nbn) * 32;
    int bcol = (blockIdx.x % nbn) * 32;
    int tx = threadIdx.x & 31;
    int ty4 = threadIdx.x >> 5;
    float acc[4] = {0.f, 0.f, 0.f, 0.f};
    for (int kt = 0; kt < K; kt += 32) {
#pragma unroll
        for (int i = 0; i < 4; ++i) {
            int idx = threadIdx.x + i * 256;
            int r = idx >> 5, c = idx & 31;
            Xs[r][c] = X[(size_t)(brow + r) * K + kt + c];
            float wv = W[(size_t)(bcol + r) * K + kt + c];
            float t = wv / speps;
            t = fminf(fmaxf(t, -1.f), 1.f);
            Ws[r][c] = rintf(t);
        }
        __syncthreads();
#pragma unroll
        for (int kk = 0; kk < 32; ++kk) {
            float wv = Ws[tx][kk];
#pragma unroll
            for (int i = 0; i < 4; ++i) acc[i] += Xs[ty4 * 4 + i][kk] * wv;
        }
        __syncthreads();
    }
    float scale = sc[0];
#pragma unroll
    for (int i = 0; i < 4; ++i)
        C[(size_t)(brow + ty4 * 4 + i) * N + (bcol + tx)] = acc[i] * scale;
}

// ---------------------------------------------------------------------------
extern "C" void kernel_launch(void* const* d_in, const int* in_sizes, int n_in,
                              void* d_out, int out_size, void* d_ws,
                              size_t ws_size, hipStream_t stream) {
    const float* x = (const float*)d_in[0];   // [B,S,K] f32
    const float* w = (const float*)d_in[1];   // [N,K]   f32
    float* out = (float*)d_out;               // [B,S,N] f32

    const int K = 4096;
    const int N = 4096;
    int xn = in_sizes[0];                     // M*K
    int wn = in_sizes[1];                     // N*K
    int M = xn / K;

    const int NPART = 2048;
    size_t off_sc = (size_t)NPART * 8;        // 16384
    size_t off_mx = off_sc + 64;              // maxv: M floats
    size_t off_xq = off_mx + (size_t)M * 4;
    off_xq = (off_xq + 63) & ~(size_t)63;
    size_t need = off_xq + (size_t)xn + (size_t)wn;  // i8 buffers

    bool shape_ok = (M % 256 == 0) && (N % 256 == 0) && (K % 256 == 0) &&
                    (K >= 512);

    if (ws_size >= need && shape_ok) {
        double* partials = (double*)d_ws;
        float* sc = (float*)((char*)d_ws + off_sc);
        float* maxv = (float*)((char*)d_ws + off_mx);
        char* xq = (char*)d_ws + off_xq;
        char* wq = xq + xn;

        absmean_partial_k<<<NPART, 256, 0, stream>>>(w, partials);
        absmean_final_k<<<1, 256, 0, stream>>>(partials, sc, NPART, wn);
        quantize_w_i8_k<<<wn / 4096, 256, 0, stream>>>(w, wq, sc);
        quantize_x_fused_k<<<M, 256, 0, stream>>>(x, xq, maxv, K);

        hipFuncSetAttribute(reinterpret_cast<const void*>(gemm8_k),
                            hipFuncAttributeMaxDynamicSharedMemorySize, 131072);
        dim3 grid((M / 256) * (N / 256));
        gemm8_k<<<grid, 512, 131072, stream>>>(xq, wq, out, sc, maxv, M, N, K);
    } else {
        double* partials = (double*)d_out;
        float* sc = (float*)d_ws;
        absmean_partial_k<<<NPART, 256, 0, stream>>>(w, partials);
        absmean_final_k<<<1, 256, 0, stream>>>(partials, sc, NPART, wn);
        dim3 grid((M / 32) * (N / 32));
        gemm_fallback_k<<<grid, 256, 0, stream>>>(x, w, out, sc, M, N, K);
    }
}